// Round 1
// baseline (467.118 us; speedup 1.0000x reference)
//
#include <hip/hip_runtime.h>

// Depthwise 1D conv (cross-correlation), SAME padding (pad_left = 4).
// x: (B=8, F=64, L=131072) f32 ; kernel: (F, 1, K=9) f32
// out: (F, B, 1, L) f32 -> out[(f*B + b)*L + l]
//
// v2: 4096-element chunk per block (was 1024). Stage chunk + 8-elem halo
// (4104 floats) into LDS via exactly-once aligned float4 loads (4 per thread
// + 2-thread tail -> 4x the in-flight loads per wave before the barrier),
// then 4 sequential compute groups of 1024 outputs each: 3x ds_read_b128,
// 36 FMA, 1 nontemporal float4 store. Quarters block count (16,384) and
// barrier count; halo overhead 1.002x. Stores are nontemporal: the out
// stream is never re-read, keep L2 for the x halo.
// Global traffic = 1.002x read + 1x write — the memory-bound minimum.

#define BB 8
#define FF 64
#define LL 131072
#define KK 9
#define CHUNK 4096
#define CPR (LL / CHUNK)      // 32 chunks per row
#define CPR_SHIFT 5
#define NROWS (BB * FF)       // 512
#define LDS_N (CHUNK + 8)     // 4104 floats staged (x[l0-4 .. l0+4099])
#define SUB 1024              // outputs per compute group (256 thr * 4)
#define NSUB (CHUNK / SUB)    // 4 groups

typedef float __attribute__((ext_vector_type(4))) floatx4;

__global__ __launch_bounds__(256, 8) void dwconv1d_kernel(
    const float* __restrict__ x,
    const float* __restrict__ kern,
    float* __restrict__ out)
{
    __shared__ float s[LDS_N];

    const int c       = blockIdx.x;
    const int chunk   = c & (CPR - 1);
    const int row_out = c >> CPR_SHIFT;   // f*8 + b, in [0, 512)
    const int f       = row_out >> 3;
    const int b       = row_out & 7;

    const float* xrow = x + ((size_t)(b * FF + f)) * (size_t)LL;
    const int l0 = chunk << 12;           // chunk * 4096
    const int t  = threadIdx.x;

    // Stage s[j] = x[l0 - 4 + j], j in [0, 4104), zero outside [0, L).
    // 1026 aligned float4 loads: 4 per thread + 2-thread tail. l0-4 is
    // 4-aligned so no straddle: each float4 is fully in or fully out
    // (only at row edges).
    #pragma unroll
    for (int i = 0; i < 4; ++i) {
        const int v = t + 256 * i;        // < 1024 always
        const int g = l0 - 4 + 4 * v;     // global float index of s[4v..4v+3]
        float4 val = make_float4(0.f, 0.f, 0.f, 0.f);
        if (g >= 0 && g + 3 < LL) val = *(const float4*)(xrow + g);
        *(float4*)(&s[4 * v]) = val;
    }
    if (t < 2) {
        const int v = t + 1024;           // 1024, 1025
        const int g = l0 - 4 + 4 * v;
        float4 val = make_float4(0.f, 0.f, 0.f, 0.f);
        if (g >= 0 && g + 3 < LL) val = *(const float4*)(xrow + g);
        *(float4*)(&s[4 * v]) = val;
    }

    // Weights: f is block-uniform -> scalar loads, L1/K$ resident.
    float w[KK];
    #pragma unroll
    for (int k = 0; k < KK; ++k) w[k] = kern[f * KK + k];

    __syncthreads();

    float* orow = out + (size_t)row_out * (size_t)LL + l0;

    // Group g, thread t computes outputs l0 + 1024g + 4t .. +3:
    //   out[l0+i] = sum_k w[k] * x[l0+i-4+k] = sum_k w[k] * s[i+k]
    // Sequential groups keep liveness at one 12-float window + 4 acc.
    #pragma unroll
    for (int grp = 0; grp < NSUB; ++grp) {
        const int base = SUB * grp + 4 * t;

        float xin[12];
        #pragma unroll
        for (int m = 0; m < 12; ++m) xin[m] = s[base + m];

        float acc[4];
        #pragma unroll
        for (int j = 0; j < 4; ++j) {
            float v0 = 0.f;
            #pragma unroll
            for (int k = 0; k < KK; ++k) v0 += w[k] * xin[j + k];
            acc[j] = v0;
        }

        floatx4 o = { acc[0], acc[1], acc[2], acc[3] };
        __builtin_nontemporal_store(o, (floatx4*)(orow + base));
    }
}

extern "C" void kernel_launch(void* const* d_in, const int* in_sizes, int n_in,
                              void* d_out, int out_size, void* d_ws, size_t ws_size,
                              hipStream_t stream) {
    const float* x    = (const float*)d_in[0];
    const float* kern = (const float*)d_in[1];
    float* out        = (float*)d_out;

    const int grid  = NROWS * CPR;   // 16,384 blocks
    const int block = 256;

    hipLaunchKernelGGL(dwconv1d_kernel, dim3(grid), dim3(block), 0, stream,
                       x, kern, out);
}

// Round 2
// 445.041 us; speedup vs baseline: 1.0496x; 1.0496x over previous
//
#include <hip/hip_runtime.h>

// Depthwise 1D conv (cross-correlation), SAME padding (pad_left = 4).
// x: (B=8, F=64, L=131072) f32 ; kernel: (F, 1, K=9) f32
// out: (F, B, 1, L) f32 -> out[(f*B + b)*L + l]
//
// v3: direct-from-global, no LDS, no barrier. With K=9 the halo is +-4
// floats, so each thread's 4-output quad needs x[l-4 .. l+7] = three
// aligned float4 loads at p-4, p, p+4. Each of those is a fully
// contiguous 1KB wave transaction (16B/lane, 64 lanes), mutually
// overlapping by 1008B -> the 3x read amplification is absorbed by
// L1/L2; HBM sees each line once. This removes v2's suspects wholesale:
// LDS bank conflicts (1.68e7 -> 0), the staging barrier (full
// vmcnt-drain per block), and nontemporal stores.
// 2 quads per thread (CHUNK=2048) -> 6 independent loads in flight per
// thread before any compute. Edge handling is block-uniform: only
// chunks 0 and 63 of each row take the checked path, and because quads
// are 4-aligned every halo float4 is either fully in-bounds or fully
// out (zero) -- bit-exact SAME padding.

#define BB 8
#define FF 64
#define LL 131072
#define KK 9
#define CHUNK 2048
#define CPR (LL / CHUNK)      // 64 chunks per row
#define CPR_SHIFT 6
#define NROWS (BB * FF)       // 512
#define QPT 2                 // output quads (4 floats) per thread

__global__ __launch_bounds__(256) void dwconv1d_kernel(
    const float* __restrict__ x,
    const float* __restrict__ kern,
    float* __restrict__ out)
{
    const int c       = blockIdx.x;
    const int chunk   = c & (CPR - 1);
    const int row_out = c >> CPR_SHIFT;   // f*8 + b, in [0, 512)
    const int f       = row_out >> 3;
    const int b       = row_out & 7;

    const float* __restrict__ xrow = x + ((size_t)(b * FF + f)) * (size_t)LL;
    float* __restrict__ orow       = out + (size_t)row_out * (size_t)LL;

    const int l0    = chunk << 11;        // chunk * 2048
    const int t     = threadIdx.x;
    const int base0 = l0 + 4 * t;         // quad q covers base0 + 1024q .. +3

    // Weights: f is block-uniform -> scalar loads, K$-resident.
    float w[KK];
    #pragma unroll
    for (int k = 0; k < KK; ++k) w[k] = kern[f * KK + k];

    float4 va[QPT], vb[QPT], vc[QPT];

    if (chunk != 0 && chunk != CPR - 1) {
        // Interior: no bounds checks at all. 6 independent loads issue
        // back-to-back; each instruction is a contiguous 1KB wave read.
        #pragma unroll
        for (int q = 0; q < QPT; ++q) {
            const float* p = xrow + base0 + 1024 * q;
            va[q] = *(const float4*)(p - 4);
            vb[q] = *(const float4*)(p);
            vc[q] = *(const float4*)(p + 4);
        }
    } else {
        // Row edges: halo float4s are 4-aligned -> fully in or fully out.
        #pragma unroll
        for (int q = 0; q < QPT; ++q) {
            const int l    = base0 + 1024 * q;
            const float* p = xrow + l;
            va[q] = (l - 4 >= 0) ? *(const float4*)(p - 4)
                                 : make_float4(0.f, 0.f, 0.f, 0.f);
            vb[q] = *(const float4*)(p);
            vc[q] = (l + 7 < LL) ? *(const float4*)(p + 4)
                                 : make_float4(0.f, 0.f, 0.f, 0.f);
        }
    }

    #pragma unroll
    for (int q = 0; q < QPT; ++q) {
        const float xin[12] = { va[q].x, va[q].y, va[q].z, va[q].w,
                                vb[q].x, vb[q].y, vb[q].z, vb[q].w,
                                vc[q].x, vc[q].y, vc[q].z, vc[q].w };
        float acc[4];
        #pragma unroll
        for (int j = 0; j < 4; ++j) {
            float v0 = 0.f;
            #pragma unroll
            for (int k = 0; k < KK; ++k) v0 += w[k] * xin[j + k];
            acc[j] = v0;
        }
        *(float4*)(orow + base0 + 1024 * q) =
            make_float4(acc[0], acc[1], acc[2], acc[3]);
    }
}

extern "C" void kernel_launch(void* const* d_in, const int* in_sizes, int n_in,
                              void* d_out, int out_size, void* d_ws, size_t ws_size,
                              hipStream_t stream) {
    const float* x    = (const float*)d_in[0];
    const float* kern = (const float*)d_in[1];
    float* out        = (float*)d_out;

    const int grid  = NROWS * CPR;   // 32,768 blocks
    const int block = 256;

    hipLaunchKernelGGL(dwconv1d_kernel, dim3(grid), dim3(block), 0, stream,
                       x, kern, out);
}